// Round 4
// baseline (377.020 us; speedup 1.0000x reference)
//
#include <hip/hip_runtime.h>

#define E_EDGES   1000000
#define NNODES    2048
#define HCH       128
#define KPW       168                 // LDS A row stride in shorts (336 B)
#define TILE      64
#define NSPREAD   8
#define GRID_GEMM 768                 // 96 blocks per XCD-group (bid&7)
#define JPG       96                  // blocks per group
#define ZVEC      (32 * 2048 * 64 / 4)
#define ZBLK      512
#define SORTB     256
#define SCH       3907                // ceil(1e6/256) edges per sort block
#define PADCAP    1000512             // >= 1e6 + 8*63, multiple of 64

typedef short  shortx8 __attribute__((ext_vector_type(8)));
typedef float  floatx4 __attribute__((ext_vector_type(4)));

__device__ __forceinline__ unsigned int f2bf(float f) {
  union { float f; unsigned int u; } v; v.f = f;
  return (v.u + 0x7fffu + ((v.u >> 16) & 1u)) >> 16;   // RNE, low 16 bits valid
}

// ---------------------------------------------------------------- prep ----
__global__ void k_prep(const float* __restrict__ z, const float* __restrict__ W1,
                       const float* __restrict__ b1,
                       unsigned short* __restrict__ zb, unsigned short* __restrict__ w1t,
                       float* __restrict__ gstats) {
  int bid = blockIdx.x;
  if (bid < ZBLK) {
    const float4* z4 = (const float4*)z;
    ushort4* zb4 = (ushort4*)zb;
    for (int i = bid * 256 + threadIdx.x; i < ZVEC; i += ZBLK * 256) {
      float4 v = z4[i];
      ushort4 o;
      o.x = (unsigned short)f2bf(v.x); o.y = (unsigned short)f2bf(v.y);
      o.z = (unsigned short)f2bf(v.z); o.w = (unsigned short)f2bf(v.w);
      zb4[i] = o;
    }
  } else if (bid == ZBLK) {
    for (int idx = threadIdx.x; idx < 132 * HCH; idx += 256) {
      int k = idx >> 7, n = idx & 127;
      w1t[n * KPW + k] = (unsigned short)f2bf(W1[idx]);
    }
    for (int idx = threadIdx.x; idx < HCH * (KPW - 132); idx += 256) {
      int n = idx / (KPW - 132);
      int k = 132 + (idx - n * (KPW - 132));
      w1t[n * KPW + k] = (k == 132) ? (unsigned short)f2bf(b1[n]) : (unsigned short)0;
    }
  } else {
    for (int i = threadIdx.x; i < NSPREAD * 2 * HCH; i += 256) gstats[i] = 0.f;
  }
}

// ------------------------------------------------------- sort: histogram ----
__global__ void k_hist(const int* __restrict__ ei, int* __restrict__ blk) {
  __shared__ int c[32];
  int tid = threadIdx.x, b = blockIdx.x;
  if (tid < 32) c[tid] = 0;
  __syncthreads();
  int e0 = b * SCH, e1 = min(e0 + SCH, E_EDGES);
  for (int e = e0 + tid; e < e1; e += 256)
    atomicAdd(&c[ei[e] >> 11], 1);
  __syncthreads();
  if (tid < 32) blk[tid * SORTB + b] = c[tid];
}

// ------------------------------------------------------------ sort: scan ----
// One block. Exclusive scan over 32x256 counts (k-major), build 64-aligned
// padded group ranges (4 batches/group), write per-(k,b) bases + Gtab + pads.
__global__ void k_scan(int* __restrict__ blk, int* __restrict__ Gtab,
                       uint4* __restrict__ rrec, ushort4* __restrict__ rattr) {
  __shared__ int sc[32 * SORTB];
  __shared__ int tsum[256];
  __shared__ int PGs[9], graws[9];
  int tid = threadIdx.x;
  for (int i = 0; i < 32; ++i) sc[tid * 32 + i] = blk[tid * 32 + i];
  int s = 0;
  for (int i = 0; i < 32; ++i) { int v = sc[tid * 32 + i]; sc[tid * 32 + i] = s; s += v; }
  tsum[tid] = s;
  __syncthreads();
  if (tid == 0) {
    int run = 0;
    for (int i = 0; i < 256; ++i) { int v = tsum[i]; tsum[i] = run; run += v; }
    for (int g = 0; g < 8; ++g) graws[g] = tsum[32 * g];
    graws[8] = run;                                  // == E_EDGES
    PGs[0] = 0;
    for (int g = 0; g < 8; ++g) {
      int len = graws[g + 1] - graws[g];
      PGs[g + 1] = PGs[g] + ((len + 63) & ~63);
    }
    for (int g = 0; g < 9; ++g) Gtab[g] = PGs[g];
  }
  __syncthreads();
  int base = tsum[tid];
  for (int i = 0; i < 32; ++i) {
    int idx = tid * 32 + i;
    int g = idx >> 10;                               // k>>2, k = idx>>8
    blk[idx] = PGs[g] + base + sc[idx] - graws[g];
  }
  for (int g = 0; g < 8; ++g) {
    int ps = PGs[g] + (graws[g + 1] - graws[g]);
    int pe = PGs[g + 1];
    for (int p = ps + tid; p < pe; p += 256) {
      rrec[p]  = (uint4){0u, 0u, 0xFFFFFFFFu, 0u};
      rattr[p] = (ushort4){0, 0, 0, 0};
    }
  }
}

// --------------------------------------------------------- sort: scatter ----
__global__ void k_scatter(const int* __restrict__ ei, const float* __restrict__ attr,
                          const int* __restrict__ blkoff,
                          uint4* __restrict__ rrec, ushort4* __restrict__ rattr) {
  __shared__ int c[32];
  int tid = threadIdx.x, b = blockIdx.x;
  if (tid < 32) c[tid] = blkoff[tid * SORTB + b];
  __syncthreads();
  int e0 = b * SCH, e1 = min(e0 + SCH, E_EDGES);
  for (int e = e0 + tid; e < e1; e += 256) {
    int sv = ei[e], dv = ei[E_EDGES + e];
    int pos = atomicAdd(&c[sv >> 11], 1);
    float4 a = ((const float4*)attr)[e];
    rrec[pos] = (uint4){(unsigned)sv,
                        (unsigned)((sv & ~(NNODES - 1)) | (dv & (NNODES - 1))),
                        (unsigned)e, 0u};
    rattr[pos] = (ushort4){(unsigned short)f2bf(a.x), (unsigned short)f2bf(a.y),
                           (unsigned short)f2bf(a.z), (unsigned short)f2bf(a.w)};
  }
}

// ---------------------------------------------------------------- gemm ----
// Sorted records: block bid handles tiles of batch-group (bid&7) with stride
// 96 -> each XCD gathers from a ~1MB L2-resident slice of zb. Same pipelined
// double-buffer structure as R3 (one barrier/tile). Pad records (orig=-1)
// stage fully-zero A rows (h=0 -> stats exact); OUT pass scatters out[orig].
template<bool OUT>
__global__ __launch_bounds__(256, 3)
void k_gemm(const unsigned short* __restrict__ zb,
            const unsigned short* __restrict__ w1t,
            const uint4* __restrict__ rrec,
            const ushort4* __restrict__ rattr,
            const int* __restrict__ Gtab,
            float* __restrict__ gstats,
            const float* __restrict__ gamma,
            const float* __restrict__ beta,
            const float* __restrict__ W2,
            const float* __restrict__ b2,
            float* __restrict__ out) {
  __shared__ __align__(16) unsigned short A[2][TILE * KPW];   // 43008 B
  __shared__ float s_sum[HCH], s_sq[HCH];
  __shared__ float po[2][TILE];
  __shared__ int   so[3][TILE];

  const int tid  = threadIdx.x;
  const int lane = tid & 63;
  const int l15  = lane & 15;
  const int quad = lane >> 4;
  const int wave = tid >> 6;
  const int eh   = wave >> 1;
  const int nh   = wave & 1;
  const int bid  = blockIdx.x;
  const int eloc = tid >> 2;
  const int q    = tid & 3;

  // ---- B fragments in registers
  shortx8 bfr[4][5];
#pragma unroll
  for (int nt = 0; nt < 4; ++nt) {
    const unsigned short* bp = w1t + (nh * 64 + nt * 16 + l15) * KPW + quad * 8;
#pragma unroll
    for (int kk = 0; kk < 5; ++kk)
      bfr[nt][kk] = *(const shortx8*)(bp + kk * 32);
  }

  float ea[4], ebb[4], ew2[4], b2v = 0.f;
  float ssum[4] = {0.f, 0.f, 0.f, 0.f}, ssq[4] = {0.f, 0.f, 0.f, 0.f};
  if (OUT) {
#pragma unroll
    for (int nt = 0; nt < 4; ++nt) {
      int c = nh * 64 + nt * 16 + l15;
      float S = 0.f, Q = 0.f;
#pragma unroll
      for (int i = 0; i < NSPREAD; ++i) {
        S += gstats[i * 2 * HCH + c];
        Q += gstats[i * 2 * HCH + HCH + c];
      }
      float inv = 1.0f / (float)E_EDGES;
      float mu  = S * inv;
      float var = Q * inv - mu * mu;
      float a   = gamma[c] * rsqrtf(var + 1e-5f);
      ea[nt]  = a;
      ebb[nt] = beta[c] - mu * a;
      ew2[nt] = W2[c];
    }
    b2v = b2[0];
  } else {
    if (tid < HCH) { s_sum[tid] = 0.f; s_sq[tid] = 0.f; }
  }

  // zero the constant K-pad region (bytes 272..335 of each row), both bufs
  for (int i = tid; i < 2 * TILE * 4; i += 256) {
    int b = i >> 8, r = (i >> 2) & 63, c = i & 3;
    *(uint4*)((char*)&A[b][r * KPW] + 272 + c * 16) = (uint4){0u, 0u, 0u, 0u};
  }

  const int grp  = bid & 7;
  const int jblk = bid >> 3;
  const int tBeg = Gtab[grp] >> 6;
  const int tEnd = Gtab[grp + 1] >> 6;

  int t = tBeg + jblk;
  const bool active = (t < tEnd);

  int pcur = 0, wr = 0;
  float prevT[2][4];
  bool havePrev = false;
  uint4 recN;              // record used for gather of next tile (this thread)
  uint4 st[4];

  if (active) {
    // ---------------- prologue: tile t into buf0 ----------------
    uint4 recC = rrec[t * TILE + eloc];
    {
      int row = (q >= 2) ? (int)recC.y : (int)recC.x;
      const uint4* src = (const uint4*)((const char*)zb + row * 128 + (q & 1) * 64);
      st[0] = src[0]; st[1] = src[1]; st[2] = src[2]; st[3] = src[3];
    }
    uint4 r2; ushort4 a2;
    if (tid < TILE) { r2 = rrec[t * TILE + tid]; a2 = rattr[t * TILE + tid]; }
    {
      int t1 = (t + JPG < tEnd) ? t + JPG : tBeg;
      recN = rrec[t1 * TILE + eloc];
    }
    if (recC.z == 0xFFFFFFFFu) { st[0] = st[1] = st[2] = st[3] = (uint4){0,0,0,0}; }
    {
      char* dst = (char*)&A[0][eloc * KPW] + q * 64;
      ((uint4*)dst)[0] = st[0]; ((uint4*)dst)[1] = st[1];
      ((uint4*)dst)[2] = st[2]; ((uint4*)dst)[3] = st[3];
      if (tid < TILE) {
        so[2][tid] = (int)r2.z;
        uint4 v;
        if (r2.z == 0xFFFFFFFFu) v = (uint4){0u, 0u, 0u, 0u};
        else {
          v.x = (unsigned)a2.x | ((unsigned)a2.y << 16);
          v.y = (unsigned)a2.z | ((unsigned)a2.w << 16);
          v.z = 0x3F80u; v.w = 0u;
        }
        *(uint4*)((char*)&A[0][tid * KPW] + 256) = v;
      }
    }
    __syncthreads();

    // ---------------- main loop ----------------
    for (; t < tEnd; t += JPG) {
      const int pn  = pcur ^ 1;
      const int tn  = (t + JPG < tEnd) ? t + JPG : tBeg;
      const int tnn = (tn + JPG < tEnd) ? tn + JPG : tBeg;

      // 1. gather(tn) into VGPRs (latency hides under K-loop)
      {
        int row = (q >= 2) ? (int)recN.y : (int)recN.x;
        const uint4* src = (const uint4*)((const char*)zb + row * 128 + (q & 1) * 64);
        st[0] = src[0]; st[1] = src[1]; st[2] = src[2]; st[3] = src[3];
      }
      uint4 r2n; ushort4 a2n;
      if (tid < TILE) { r2n = rrec[tn * TILE + tid]; a2n = rattr[tn * TILE + tid]; }

      // 2. record prefetch for tnn
      uint4 recNN = rrec[tnn * TILE + eloc];

      // 2.5 OUT: flush previous tile's result (scatter by orig index)
      if (OUT && havePrev && nh == 0 && l15 == 0) {
        int rs = wr + 1; if (rs == 3) rs = 0;
#pragma unroll
        for (int mt = 0; mt < 2; ++mt)
#pragma unroll
          for (int r = 0; r < 4; ++r) {
            int el = eh * 32 + mt * 16 + quad * 4 + r;
            int og = so[rs][el];
            if (og != -1)
              out[og] = prevT[mt][r] + po[pcur ^ 1][el] + b2v;
          }
      }

      // 3. K-loop on buf pcur
      floatx4 acc[2][4];
#pragma unroll
      for (int mt = 0; mt < 2; ++mt)
#pragma unroll
        for (int nt = 0; nt < 4; ++nt)
          acc[mt][nt] = (floatx4){0.f, 0.f, 0.f, 0.f};

#pragma unroll
      for (int kk = 0; kk < 5; ++kk) {
        shortx8 afr0 = *(const shortx8*)(&A[pcur][(eh * 32 + l15) * KPW + kk * 32 + quad * 8]);
        shortx8 afr1 = *(const shortx8*)(&A[pcur][(eh * 32 + 16 + l15) * KPW + kk * 32 + quad * 8]);
#pragma unroll
        for (int nt = 0; nt < 4; ++nt) {
          acc[0][nt] = __builtin_amdgcn_mfma_f32_16x16x32_bf16(afr0, bfr[nt][kk], acc[0][nt], 0, 0, 0);
          acc[1][nt] = __builtin_amdgcn_mfma_f32_16x16x32_bf16(afr1, bfr[nt][kk], acc[1][nt], 0, 0, 0);
        }
      }

      // 4. epilogue (C/D: col = lane&15 = channel, row = quad*4 + reg = edge)
      if (!OUT) {
#pragma unroll
        for (int nt = 0; nt < 4; ++nt) {
          float s = 0.f, qq = 0.f;
#pragma unroll
          for (int mt = 0; mt < 2; ++mt)
#pragma unroll
            for (int r = 0; r < 4; ++r) {
              float h = acc[mt][nt][r];
              s += h; qq += h * h;
            }
          ssum[nt] += s; ssq[nt] += qq;
        }
      } else {
        float tpart[2][4];
#pragma unroll
        for (int mt = 0; mt < 2; ++mt)
#pragma unroll
          for (int r = 0; r < 4; ++r) {
            float tv = 0.f;
#pragma unroll
            for (int nt = 0; nt < 4; ++nt) {
              float h = acc[mt][nt][r];
              float p = ea[nt] * h + ebb[nt];
              p = (p >= 0.f) ? p : 0.2f * p;
              tv += p * ew2[nt];
            }
            tv += __shfl_xor(tv, 1);
            tv += __shfl_xor(tv, 2);
            tv += __shfl_xor(tv, 4);
            tv += __shfl_xor(tv, 8);
            tpart[mt][r] = tv;
          }
        if (nh == 1 && l15 == 0) {
#pragma unroll
          for (int mt = 0; mt < 2; ++mt)
#pragma unroll
            for (int r = 0; r < 4; ++r)
              po[pcur][eh * 32 + mt * 16 + quad * 4 + r] = tpart[mt][r];
        }
        if (nh == 0) {
#pragma unroll
          for (int mt = 0; mt < 2; ++mt)
#pragma unroll
            for (int r = 0; r < 4; ++r)
              prevT[mt][r] = tpart[mt][r];
        }
        havePrev = true;
      }

      // 5-6. stage tile tn -> buf pn (pad rows fully zeroed)
      if (recN.z == 0xFFFFFFFFu) { st[0] = st[1] = st[2] = st[3] = (uint4){0,0,0,0}; }
      {
        char* dst = (char*)&A[pn][eloc * KPW] + q * 64;
        ((uint4*)dst)[0] = st[0]; ((uint4*)dst)[1] = st[1];
        ((uint4*)dst)[2] = st[2]; ((uint4*)dst)[3] = st[3];
        if (tid < TILE) {
          so[wr][tid] = (int)r2n.z;
          uint4 v;
          if (r2n.z == 0xFFFFFFFFu) v = (uint4){0u, 0u, 0u, 0u};
          else {
            v.x = (unsigned)a2n.x | ((unsigned)a2n.y << 16);
            v.y = (unsigned)a2n.z | ((unsigned)a2n.w << 16);
            v.z = 0x3F80u; v.w = 0u;
          }
          *(uint4*)((char*)&A[pn][tid * KPW] + 256) = v;
        }
      }
      recN = recNN;

      // 7. single barrier per tile
      __syncthreads();
      pcur ^= 1;
      wr = (wr + 1 == 3) ? 0 : wr + 1;
    }
  }

  if (OUT) {
    if (havePrev && nh == 0 && l15 == 0) {
      int rs = wr + 1; if (rs == 3) rs = 0;
#pragma unroll
      for (int mt = 0; mt < 2; ++mt)
#pragma unroll
        for (int r = 0; r < 4; ++r) {
          int el = eh * 32 + mt * 16 + quad * 4 + r;
          int og = so[rs][el];
          if (og != -1)
            out[og] = prevT[mt][r] + po[pcur ^ 1][el] + b2v;
        }
    }
  } else {
#pragma unroll
    for (int nt = 0; nt < 4; ++nt) {
      float s = ssum[nt], qv = ssq[nt];
      s  += __shfl_xor(s, 16);  s  += __shfl_xor(s, 32);
      qv += __shfl_xor(qv, 16); qv += __shfl_xor(qv, 32);
      if (quad == 0) {
        atomicAdd(&s_sum[nh * 64 + nt * 16 + l15], s);
        atomicAdd(&s_sq [nh * 64 + nt * 16 + l15], qv);
      }
    }
    __syncthreads();
    float* dstc = gstats + (bid & (NSPREAD - 1)) * 2 * HCH;
    if (tid < HCH)          atomicAdd(&dstc[tid], s_sum[tid]);
    else if (tid < 2 * HCH) atomicAdd(&dstc[tid], s_sq[tid - HCH]);
  }
}

// -------------------------------------------------------------- launch ----
extern "C" void kernel_launch(void* const* d_in, const int* in_sizes, int n_in,
                              void* d_out, int out_size, void* d_ws, size_t ws_size,
                              hipStream_t stream) {
  const float* z     = (const float*)d_in[0];
  const float* attr  = (const float*)d_in[1];
  const float* W1    = (const float*)d_in[2];
  const float* b1    = (const float*)d_in[3];
  const float* gamma = (const float*)d_in[4];
  const float* beta  = (const float*)d_in[5];
  const float* W2    = (const float*)d_in[6];
  const float* b2    = (const float*)d_in[7];
  const int*   ei    = (const int*)d_in[8];
  float* out = (float*)d_out;

  char* ws = (char*)d_ws;
  unsigned short* zb  = (unsigned short*)ws;                   // 8,388,608 B
  unsigned short* w1t = (unsigned short*)(ws + 8388608);       //    43,008 B
  float* gstats       = (float*)(ws + 8431616);                //     8,192 B
  int*   blk          = (int*)(ws + 8439808);                  //    32,768 B
  int*   Gtab         = (int*)(ws + 8472576);                  //        64 B
  uint4* rrec         = (uint4*)(ws + 8472640);                // 16,008,192 B
  ushort4* rattr      = (ushort4*)(ws + 24480832);             //  8,004,096 B
  // total ~32.5 MB

  k_prep<<<ZBLK + 2, 256, 0, stream>>>(z, W1, b1, zb, w1t, gstats);
  k_hist<<<SORTB, 256, 0, stream>>>(ei, blk);
  k_scan<<<1, 256, 0, stream>>>(blk, Gtab, rrec, rattr);
  k_scatter<<<SORTB, 256, 0, stream>>>(ei, attr, blk, rrec, rattr);
  k_gemm<false><<<GRID_GEMM, 256, 0, stream>>>(zb, w1t, rrec, rattr, Gtab, gstats,
                                               gamma, beta, W2, b2, nullptr);
  k_gemm<true><<<GRID_GEMM, 256, 0, stream>>>(zb, w1t, rrec, rattr, Gtab, gstats,
                                              gamma, beta, W2, b2, out);
}

// Round 5
// 342.638 us; speedup vs baseline: 1.1003x; 1.1003x over previous
//
#include <hip/hip_runtime.h>

#define E_EDGES   1000000
#define NNODES    2048
#define HCH       128
#define KPW       168                 // LDS A row stride in shorts (336 B)
#define TILE      64
#define NSPREAD   8
#define GRID_GEMM 768
#define ZVEC      (32 * 2048 * 64 / 4)
#define ZBLK      512
#define SORTB     256
#define SCH       3907                // ceil(1e6/256) edges per sort block
#define PADCAP    1000512

typedef short  shortx8 __attribute__((ext_vector_type(8)));
typedef float  floatx4 __attribute__((ext_vector_type(4)));

__device__ __forceinline__ unsigned int f2bf(float f) {
  union { float f; unsigned int u; } v; v.f = f;
  return (v.u + 0x7fffu + ((v.u >> 16) & 1u)) >> 16;   // RNE, low 16 bits valid
}

// ------------------------------------------------- prep (+fused histogram) ----
__global__ void k_prep(const float* __restrict__ z, const float* __restrict__ W1,
                       const float* __restrict__ b1, const int* __restrict__ ei,
                       unsigned short* __restrict__ zb, unsigned short* __restrict__ w1t,
                       float* __restrict__ gstats, int* __restrict__ blk) {
  __shared__ int c[32];
  int bid = blockIdx.x, tid = threadIdx.x;
  if (bid < ZBLK) {
    const float4* z4 = (const float4*)z;
    ushort4* zb4 = (ushort4*)zb;
    for (int i = bid * 256 + tid; i < ZVEC; i += ZBLK * 256) {
      float4 v = z4[i];
      ushort4 o;
      o.x = (unsigned short)f2bf(v.x); o.y = (unsigned short)f2bf(v.y);
      o.z = (unsigned short)f2bf(v.z); o.w = (unsigned short)f2bf(v.w);
      zb4[i] = o;
    }
  } else if (bid == ZBLK) {
    for (int idx = tid; idx < 132 * HCH; idx += 256) {
      int k = idx >> 7, n = idx & 127;
      w1t[n * KPW + k] = (unsigned short)f2bf(W1[idx]);
    }
    for (int idx = tid; idx < HCH * (KPW - 132); idx += 256) {
      int n = idx / (KPW - 132);
      int k = 132 + (idx - n * (KPW - 132));
      w1t[n * KPW + k] = (k == 132) ? (unsigned short)f2bf(b1[n]) : (unsigned short)0;
    }
  } else if (bid == ZBLK + 1) {
    for (int i = tid; i < NSPREAD * 2 * HCH; i += 256) gstats[i] = 0.f;
  } else {
    int b = bid - (ZBLK + 2);          // histogram over 32 batch keys
    if (tid < 32) c[tid] = 0;
    __syncthreads();
    int e0 = b * SCH, e1 = min(e0 + SCH, E_EDGES);
    for (int e = e0 + tid; e < e1; e += 256)
      atomicAdd(&c[ei[e] >> 11], 1);
    __syncthreads();
    if (tid < 32) blk[tid * SORTB + b] = c[tid];
  }
}

// ------------------------------------------------------------ sort: scan ----
// One block. Exclusive scan over 32x256 counts (k-major), 64-aligned padded
// group ranges (4 batches/group); rewrite blk to per-(k,b) scatter bases.
__global__ void k_scan(int* __restrict__ blk, int* __restrict__ Gtab,
                       uint2* __restrict__ rrec, ushort4* __restrict__ rattr) {
  __shared__ int sc[32 * SORTB];
  __shared__ int tsum[256];
  __shared__ int PGs[9], graws[9];
  int tid = threadIdx.x;
  for (int i = 0; i < 32; ++i) sc[tid * 32 + i] = blk[tid * 32 + i];
  int s = 0;
  for (int i = 0; i < 32; ++i) { int v = sc[tid * 32 + i]; sc[tid * 32 + i] = s; s += v; }
  tsum[tid] = s;
  __syncthreads();
  if (tid == 0) {
    int run = 0;
    for (int i = 0; i < 256; ++i) { int v = tsum[i]; tsum[i] = run; run += v; }
    for (int g = 0; g < 8; ++g) graws[g] = tsum[32 * g];
    graws[8] = run;                                  // == E_EDGES
    PGs[0] = 0;
    for (int g = 0; g < 8; ++g) {
      int len = graws[g + 1] - graws[g];
      PGs[g + 1] = PGs[g] + ((len + 63) & ~63);
    }
    for (int g = 0; g < 9; ++g) Gtab[g] = PGs[g];
  }
  __syncthreads();
  int base = tsum[tid];
  for (int i = 0; i < 32; ++i) {
    int idx = tid * 32 + i;
    int g = idx >> 10;                               // 4 batches * 256 blocks
    blk[idx] = PGs[g] + base + sc[idx] - graws[g];
  }
  for (int g = 0; g < 8; ++g) {
    int ps = PGs[g] + (graws[g + 1] - graws[g]);
    int pe = PGs[g + 1];
    for (int p = ps + tid; p < pe; p += 256) {
      rrec[p]  = (uint2){0u, 0xFFFFFFFFu};
      rattr[p] = (ushort4){0, 0, 0, 0};
    }
  }
}

// --------------------------------------------------------- sort: scatter ----
__global__ void k_scatter(const int* __restrict__ ei, const float* __restrict__ attr,
                          const int* __restrict__ blkoff,
                          uint2* __restrict__ rrec, ushort4* __restrict__ rattr) {
  __shared__ int c[32];
  int tid = threadIdx.x, b = blockIdx.x;
  if (tid < 32) c[tid] = blkoff[tid * SORTB + b];
  __syncthreads();
  int e0 = b * SCH, e1 = min(e0 + SCH, E_EDGES);
  for (int e = e0 + tid; e < e1; e += 256) {
    int sv = ei[e], dv = ei[E_EDGES + e];
    int pos = atomicAdd(&c[sv >> 11], 1);
    unsigned dr = (unsigned)((sv & ~(NNODES - 1)) | (dv & (NNODES - 1)));
    float4 a = ((const float4*)attr)[e];
    rrec[pos] = (uint2){(unsigned)sv | (dr << 16), (unsigned)e};
    rattr[pos] = (ushort4){(unsigned short)f2bf(a.x), (unsigned short)f2bf(a.y),
                           (unsigned short)f2bf(a.z), (unsigned short)f2bf(a.w)};
  }
}

// ---------------------------------------------------------------- gemm ----
// Grid-stride over BATCH-SORTED tiles: blocks stay in rough lockstep, so the
// device-wide gather window is ~1.5 MB (one-ish batch) and every XCD's L2
// holds a replica -- no workgroup->XCD mapping assumption (R4's failed).
// Same depth-2 pipeline, one barrier/tile. Pads (orig=-1) stage zero rows.
template<bool OUT>
__global__ __launch_bounds__(256, 3)
void k_gemm(const unsigned short* __restrict__ zb,
            const unsigned short* __restrict__ w1t,
            const uint2* __restrict__ rrec,
            const ushort4* __restrict__ rattr,
            const int* __restrict__ Gtab,
            float* __restrict__ gstats,
            const float* __restrict__ gamma,
            const float* __restrict__ beta,
            const float* __restrict__ W2,
            const float* __restrict__ b2,
            float* __restrict__ out) {
  __shared__ __align__(16) unsigned short A[2][TILE * KPW];   // 43008 B
  __shared__ float s_sum[HCH], s_sq[HCH];
  __shared__ float po[2][TILE];
  __shared__ int   so[3][TILE];

  const int tid  = threadIdx.x;
  const int lane = tid & 63;
  const int l15  = lane & 15;
  const int quad = lane >> 4;
  const int wave = tid >> 6;
  const int eh   = wave >> 1;
  const int nh   = wave & 1;
  const int bid  = blockIdx.x;
  const int eloc = tid >> 2;
  const int q    = tid & 3;

  const int ntp = Gtab[8] >> 6;        // padded tile count (~15633)

  // ---- B fragments in registers
  shortx8 bfr[4][5];
#pragma unroll
  for (int nt = 0; nt < 4; ++nt) {
    const unsigned short* bp = w1t + (nh * 64 + nt * 16 + l15) * KPW + quad * 8;
#pragma unroll
    for (int kk = 0; kk < 5; ++kk)
      bfr[nt][kk] = *(const shortx8*)(bp + kk * 32);
  }

  float ea[4], ebb[4], ew2[4], b2v = 0.f;
  float ssum[4] = {0.f, 0.f, 0.f, 0.f}, ssq[4] = {0.f, 0.f, 0.f, 0.f};
  if (OUT) {
#pragma unroll
    for (int nt = 0; nt < 4; ++nt) {
      int c = nh * 64 + nt * 16 + l15;
      float S = 0.f, Q = 0.f;
#pragma unroll
      for (int i = 0; i < NSPREAD; ++i) {
        S += gstats[i * 2 * HCH + c];
        Q += gstats[i * 2 * HCH + HCH + c];
      }
      float inv = 1.0f / (float)E_EDGES;
      float mu  = S * inv;
      float var = Q * inv - mu * mu;
      float a   = gamma[c] * rsqrtf(var + 1e-5f);
      ea[nt]  = a;
      ebb[nt] = beta[c] - mu * a;
      ew2[nt] = W2[c];
    }
    b2v = b2[0];
  } else {
    if (tid < HCH) { s_sum[tid] = 0.f; s_sq[tid] = 0.f; }
  }

  // zero the constant K-pad region (bytes 272..335 of each row), both bufs
  for (int i = tid; i < 2 * TILE * 4; i += 256) {
    int b = i >> 8, r = (i >> 2) & 63, c = i & 3;
    *(uint4*)((char*)&A[b][r * KPW] + 272 + c * 16) = (uint4){0u, 0u, 0u, 0u};
  }

  int t = bid;
  int pcur = 0, wr = 0;
  float prevT[2][4];
  bool havePrev = false;
  uint2 recN;
  uint4 st[4];

  if (t < ntp) {
    // ---------------- prologue: tile t into buf0 ----------------
    uint2 recC = rrec[t * TILE + eloc];
    {
      int row = (q >= 2) ? (int)(recC.x >> 16) : (int)(recC.x & 0xFFFFu);
      const uint4* src = (const uint4*)((const char*)zb + row * 128 + (q & 1) * 64);
      st[0] = src[0]; st[1] = src[1]; st[2] = src[2]; st[3] = src[3];
    }
    uint2 r2; ushort4 a2;
    if (tid < TILE) { r2 = rrec[t * TILE + tid]; a2 = rattr[t * TILE + tid]; }
    {
      int t1 = (t + GRID_GEMM < ntp) ? t + GRID_GEMM : 0;
      recN = rrec[t1 * TILE + eloc];
    }
    if (recC.y == 0xFFFFFFFFu) { st[0] = st[1] = st[2] = st[3] = (uint4){0,0,0,0}; }
    {
      char* dst = (char*)&A[0][eloc * KPW] + q * 64;
      ((uint4*)dst)[0] = st[0]; ((uint4*)dst)[1] = st[1];
      ((uint4*)dst)[2] = st[2]; ((uint4*)dst)[3] = st[3];
      if (tid < TILE) {
        so[2][tid] = (int)r2.y;
        uint4 v;
        if (r2.y == 0xFFFFFFFFu) v = (uint4){0u, 0u, 0u, 0u};
        else {
          v.x = (unsigned)a2.x | ((unsigned)a2.y << 16);
          v.y = (unsigned)a2.z | ((unsigned)a2.w << 16);
          v.z = 0x3F80u; v.w = 0u;
        }
        *(uint4*)((char*)&A[0][tid * KPW] + 256) = v;
      }
    }
    __syncthreads();

    // ---------------- main loop ----------------
    for (; t < ntp; t += GRID_GEMM) {
      const int pn  = pcur ^ 1;
      const int tn  = (t + GRID_GEMM < ntp) ? t + GRID_GEMM : 0;
      const int tnn = (tn + GRID_GEMM < ntp) ? tn + GRID_GEMM : 0;

      // 1. gather(tn) into VGPRs (latency hides under K-loop)
      {
        int row = (q >= 2) ? (int)(recN.x >> 16) : (int)(recN.x & 0xFFFFu);
        const uint4* src = (const uint4*)((const char*)zb + row * 128 + (q & 1) * 64);
        st[0] = src[0]; st[1] = src[1]; st[2] = src[2]; st[3] = src[3];
      }
      uint2 r2n; ushort4 a2n;
      if (tid < TILE) { r2n = rrec[tn * TILE + tid]; a2n = rattr[tn * TILE + tid]; }

      // 2. record prefetch for tnn
      uint2 recNN = rrec[tnn * TILE + eloc];

      // 2.5 OUT: flush previous tile's result (scatter by orig index)
      if (OUT && havePrev && nh == 0 && l15 == 0) {
        int rs = wr + 1; if (rs == 3) rs = 0;
#pragma unroll
        for (int mt = 0; mt < 2; ++mt)
#pragma unroll
          for (int r = 0; r < 4; ++r) {
            int el = eh * 32 + mt * 16 + quad * 4 + r;
            int og = so[rs][el];
            if (og != -1)
              out[og] = prevT[mt][r] + po[pcur ^ 1][el] + b2v;
          }
      }

      // 3. K-loop on buf pcur
      floatx4 acc[2][4];
#pragma unroll
      for (int mt = 0; mt < 2; ++mt)
#pragma unroll
        for (int nt = 0; nt < 4; ++nt)
          acc[mt][nt] = (floatx4){0.f, 0.f, 0.f, 0.f};

#pragma unroll
      for (int kk = 0; kk < 5; ++kk) {
        shortx8 afr0 = *(const shortx8*)(&A[pcur][(eh * 32 + l15) * KPW + kk * 32 + quad * 8]);
        shortx8 afr1 = *(const shortx8*)(&A[pcur][(eh * 32 + 16 + l15) * KPW + kk * 32 + quad * 8]);
#pragma unroll
        for (int nt = 0; nt < 4; ++nt) {
          acc[0][nt] = __builtin_amdgcn_mfma_f32_16x16x32_bf16(afr0, bfr[nt][kk], acc[0][nt], 0, 0, 0);
          acc[1][nt] = __builtin_amdgcn_mfma_f32_16x16x32_bf16(afr1, bfr[nt][kk], acc[1][nt], 0, 0, 0);
        }
      }

      // 4. epilogue (C/D: col = lane&15 = channel, row = quad*4 + reg = edge)
      if (!OUT) {
#pragma unroll
        for (int nt = 0; nt < 4; ++nt) {
          float s = 0.f, qq = 0.f;
#pragma unroll
          for (int mt = 0; mt < 2; ++mt)
#pragma unroll
            for (int r = 0; r < 4; ++r) {
              float h = acc[mt][nt][r];
              s += h; qq += h * h;
            }
          ssum[nt] += s; ssq[nt] += qq;
        }
      } else {
        float tpart[2][4];
#pragma unroll
        for (int mt = 0; mt < 2; ++mt)
#pragma unroll
          for (int r = 0; r < 4; ++r) {
            float tv = 0.f;
#pragma unroll
            for (int nt = 0; nt < 4; ++nt) {
              float h = acc[mt][nt][r];
              float p = ea[nt] * h + ebb[nt];
              p = (p >= 0.f) ? p : 0.2f * p;
              tv += p * ew2[nt];
            }
            tv += __shfl_xor(tv, 1);
            tv += __shfl_xor(tv, 2);
            tv += __shfl_xor(tv, 4);
            tv += __shfl_xor(tv, 8);
            tpart[mt][r] = tv;
          }
        if (nh == 1 && l15 == 0) {
#pragma unroll
          for (int mt = 0; mt < 2; ++mt)
#pragma unroll
            for (int r = 0; r < 4; ++r)
              po[pcur][eh * 32 + mt * 16 + quad * 4 + r] = tpart[mt][r];
        }
        if (nh == 0) {
#pragma unroll
          for (int mt = 0; mt < 2; ++mt)
#pragma unroll
            for (int r = 0; r < 4; ++r)
              prevT[mt][r] = tpart[mt][r];
        }
        havePrev = true;
      }

      // 5-6. stage tile tn -> buf pn (pad rows fully zeroed)
      if (recN.y == 0xFFFFFFFFu) { st[0] = st[1] = st[2] = st[3] = (uint4){0,0,0,0}; }
      {
        char* dst = (char*)&A[pn][eloc * KPW] + q * 64;
        ((uint4*)dst)[0] = st[0]; ((uint4*)dst)[1] = st[1];
        ((uint4*)dst)[2] = st[2]; ((uint4*)dst)[3] = st[3];
        if (tid < TILE) {
          so[wr][tid] = (int)r2n.y;
          uint4 v;
          if (r2n.y == 0xFFFFFFFFu) v = (uint4){0u, 0u, 0u, 0u};
          else {
            v.x = (unsigned)a2n.x | ((unsigned)a2n.y << 16);
            v.y = (unsigned)a2n.z | ((unsigned)a2n.w << 16);
            v.z = 0x3F80u; v.w = 0u;
          }
          *(uint4*)((char*)&A[pn][tid * KPW] + 256) = v;
        }
      }
      recN = recNN;

      // 7. single barrier per tile
      __syncthreads();
      pcur ^= 1;
      wr = (wr + 1 == 3) ? 0 : wr + 1;
    }
  }

  if (OUT) {
    if (havePrev && nh == 0 && l15 == 0) {
      int rs = wr + 1; if (rs == 3) rs = 0;
#pragma unroll
      for (int mt = 0; mt < 2; ++mt)
#pragma unroll
        for (int r = 0; r < 4; ++r) {
          int el = eh * 32 + mt * 16 + quad * 4 + r;
          int og = so[rs][el];
          if (og != -1)
            out[og] = prevT[mt][r] + po[pcur ^ 1][el] + b2v;
        }
    }
  } else {
#pragma unroll
    for (int nt = 0; nt < 4; ++nt) {
      float s = ssum[nt], qv = ssq[nt];
      s  += __shfl_xor(s, 16);  s  += __shfl_xor(s, 32);
      qv += __shfl_xor(qv, 16); qv += __shfl_xor(qv, 32);
      if (quad == 0) {
        atomicAdd(&s_sum[nh * 64 + nt * 16 + l15], s);
        atomicAdd(&s_sq [nh * 64 + nt * 16 + l15], qv);
      }
    }
    __syncthreads();
    float* dstc = gstats + (bid & (NSPREAD - 1)) * 2 * HCH;
    if (tid < HCH)          atomicAdd(&dstc[tid], s_sum[tid]);
    else if (tid < 2 * HCH) atomicAdd(&dstc[tid], s_sq[tid - HCH]);
  }
}

// -------------------------------------------------------------- launch ----
extern "C" void kernel_launch(void* const* d_in, const int* in_sizes, int n_in,
                              void* d_out, int out_size, void* d_ws, size_t ws_size,
                              hipStream_t stream) {
  const float* z     = (const float*)d_in[0];
  const float* attr  = (const float*)d_in[1];
  const float* W1    = (const float*)d_in[2];
  const float* b1    = (const float*)d_in[3];
  const float* gamma = (const float*)d_in[4];
  const float* beta  = (const float*)d_in[5];
  const float* W2    = (const float*)d_in[6];
  const float* b2    = (const float*)d_in[7];
  const int*   ei    = (const int*)d_in[8];
  float* out = (float*)d_out;

  char* ws = (char*)d_ws;
  unsigned short* zb  = (unsigned short*)ws;                   // 8,388,608 B
  unsigned short* w1t = (unsigned short*)(ws + 8388608);       //    43,008 B
  float* gstats       = (float*)(ws + 8431616);                //     8,192 B
  int*   blk          = (int*)(ws + 8439808);                  //    32,768 B
  int*   Gtab         = (int*)(ws + 8472576);                  //        64 B
  uint2* rrec         = (uint2*)(ws + 8472640);                //  8,004,096 B
  ushort4* rattr      = (ushort4*)(ws + 16476736);             //  8,004,096 B
  // total ~24.5 MB

  k_prep<<<ZBLK + 2 + SORTB, 256, 0, stream>>>(z, W1, b1, ei, zb, w1t, gstats, blk);
  k_scan<<<1, 256, 0, stream>>>(blk, Gtab, rrec, rattr);
  k_scatter<<<SORTB, 256, 0, stream>>>(ei, attr, blk, rrec, rattr);
  k_gemm<false><<<GRID_GEMM, 256, 0, stream>>>(zb, w1t, rrec, rattr, Gtab, gstats,
                                               gamma, beta, W2, b2, nullptr);
  k_gemm<true><<<GRID_GEMM, 256, 0, stream>>>(zb, w1t, rrec, rattr, Gtab, gstats,
                                              gamma, beta, W2, b2, out);
}